// Round 6
// baseline (175.814 us; speedup 1.0000x reference)
//
#include <hip/hip_runtime.h>

// Problem constants
#define BATCH 2048
#define FDIM  1024
#define GTILE 16
#define F4    256                 // float4 col-groups per row
#define CHUNKS 128
#define RPC   16                  // rows per chunk

// ws layout (floats) — every buffer fully written before read (poison-safe):
//   p1  [128][1024] @ 0        column partial sums of xf        (512 KB)
//   p2s [128][1024] @ 131072   column partial sums of relu      (512 KB)
//   p2q [128][1024] @ 262144   column partial sumsq             (512 KB)
//   mean[1024]      @ 393216
//   sc  [1024]      @ 394240   wp / sd
//   cc  [1024]      @ 395264   mu * sc
//   cnt [1]         @ 396288   k2 completion counter (zeroed by k1)
#define OFF_P1   0
#define OFF_P2S  131072
#define OFF_P2Q  262144
#define OFF_MEAN 393216
#define OFF_SC   394240
#define OFF_CC   395264
#define OFF_CNT  396288

__device__ __forceinline__ void v4add(float4& a, const float4& b) {
    a.x += b.x; a.y += b.y; a.z += b.z; a.w += b.w;
}

// ---- k1: column partial sums. 128 blocks x 512 thr.
// thread (cg, h): sums rows chunk*16 + h + 2r, r=0..7; LDS-combine halves.
// Also zeroes the k2 completion counter (visible at kernel boundary).
__global__ void __launch_bounds__(512) k1_colsum(const float4* __restrict__ xf,
                                                 float4* __restrict__ p1,
                                                 int* __restrict__ cnt) {
    __shared__ float4 lds[512];     // 8 KB
    const int t  = threadIdx.x;
    const int cg = t & 255;
    const int h  = t >> 8;
    const int b  = blockIdx.x;      // chunk
    if (b == 0 && t == 0) *cnt = 0;
    const float4* p = xf + (size_t)(b * RPC + h) * F4 + cg;
    float4 s = {0.f, 0.f, 0.f, 0.f};
#pragma unroll
    for (int r = 0; r < 8; ++r) v4add(s, p[(size_t)(2 * r) * F4]);
    lds[t] = s;
    __syncthreads();
    if (t < 256) {
        v4add(s, lds[t + 256]);
        p1[b * F4 + t] = s;
    }
}

// ---- k2: redundant split mean-reduce, relu partial sum/sumsq, and (last
// finishing block) the full finalize reduce -> sc, cc. Split-K style fold.
__global__ void __launch_bounds__(512) k2_relustats(const float4* __restrict__ xf,
                                                    const float4* __restrict__ p1,
                                                    const float* __restrict__ wp,
                                                    float4* __restrict__ p2s,
                                                    float4* __restrict__ p2q,
                                                    float4* __restrict__ mean4,
                                                    float* __restrict__ sc,
                                                    float* __restrict__ cc,
                                                    int* __restrict__ cnt) {
    __shared__ float4 ldsa[512];    // 8 KB
    __shared__ float4 ldsb[512];    // 8 KB
    __shared__ int s_last;
    const int t  = threadIdx.x;
    const int cg = t & 255;
    const int h  = t >> 8;
    const int b  = blockIdx.x;      // chunk

    // split redundant reduce of p1 -> mean (each half does 64 chunks)
    float4 m = {0.f, 0.f, 0.f, 0.f};
#pragma unroll 8
    for (int c = 0; c < 64; ++c) v4add(m, p1[(h * 64 + c) * F4 + cg]);
    ldsa[t] = m;
    __syncthreads();
    m = ldsa[cg];
    v4add(m, ldsa[cg + 256]);
    const float inv_n = 1.0f / (float)BATCH;
    m.x *= inv_n; m.y *= inv_n; m.z *= inv_n; m.w *= inv_n;
    if (b == 0 && t < 256) mean4[t] = m;

    // relu stats over rows chunk*16 + h + 2r
    const float4* p = xf + (size_t)(b * RPC + h) * F4 + cg;
    float4 s = {0.f, 0.f, 0.f, 0.f};
    float4 q = {0.f, 0.f, 0.f, 0.f};
#pragma unroll
    for (int r = 0; r < 8; ++r) {
        float4 v = p[(size_t)(2 * r) * F4];
        float rx = fmaxf(v.x - m.x, 0.f);
        float ry = fmaxf(v.y - m.y, 0.f);
        float rz = fmaxf(v.z - m.z, 0.f);
        float rw = fmaxf(v.w - m.w, 0.f);
        s.x += rx; s.y += ry; s.z += rz; s.w += rw;
        q.x += rx * rx; q.y += ry * ry; q.z += rz * rz; q.w += rw * rw;
    }
    __syncthreads();                 // ldsa being reused
    ldsa[t] = s; ldsb[t] = q;
    __syncthreads();
    if (t < 256) {
        v4add(s, ldsa[t + 256]);
        v4add(q, ldsb[t + 256]);
        p2s[b * F4 + t] = s;
        p2q[b * F4 + t] = q;
    }

    // ---- last-block finalize (folded k3) ----
    __syncthreads();                 // drain this block's p2 stores (vmcnt at barrier)
    if (t == 0) {
        __threadfence();             // device-scope release: flush p2 to coherence point
        s_last = (atomicAdd(cnt, 1) == CHUNKS - 1) ? 1 : 0;
    }
    __syncthreads();
    if (s_last) {
        __threadfence();             // acquire side
        const float* ps = (const float*)p2s;
        const float* pq = (const float*)p2q;
        float S0 = 0.f, Q0 = 0.f, S1 = 0.f, Q1 = 0.f;
#pragma unroll 4
        for (int c = 0; c < CHUNKS; ++c) {
            const float* rs = ps + c * FDIM;
            const float* rq = pq + c * FDIM;
            S0 += rs[t];       Q0 += rq[t];
            S1 += rs[t + 512]; Q1 += rq[t + 512];
        }
        const float w      = wp[0];
        const float inv_n1 = 1.0f / (float)(BATCH - 1);
        float mu, scale;
        mu = S0 * inv_n; scale = w * rsqrtf((Q0 - S0 * mu) * inv_n1);
        sc[t] = scale;       cc[t] = mu * scale;
        mu = S1 * inv_n; scale = w * rsqrtf((Q1 - S1 * mu) * inv_n1);
        sc[t + 512] = scale; cc[t + 512] = mu * scale;
    }
}

// ---- k4: fused normalize + 16-way tiled streaming write (proven). ----
__global__ void __launch_bounds__(256) k4_write(const float4* __restrict__ xf,
                                                const float4* __restrict__ mean,
                                                const float4* __restrict__ sc,
                                                const float4* __restrict__ cc,
                                                float4* __restrict__ out) {
    const int tid  = threadIdx.x;          // 0..255
    const int row0 = blockIdx.x * 2;       // 2 rows per block
    float4 v0 = xf[(size_t)row0 * F4 + tid];
    float4 v1 = xf[(size_t)(row0 + 1) * F4 + tid];
    float4 m = mean[tid];
    float4 a = sc[tid];
    float4 c = cc[tid];
    float4 o0, o1;
    o0.x = fmaxf(v0.x - m.x, 0.f) * a.x - c.x;
    o0.y = fmaxf(v0.y - m.y, 0.f) * a.y - c.y;
    o0.z = fmaxf(v0.z - m.z, 0.f) * a.z - c.z;
    o0.w = fmaxf(v0.w - m.w, 0.f) * a.w - c.w;
    o1.x = fmaxf(v1.x - m.x, 0.f) * a.x - c.x;
    o1.y = fmaxf(v1.y - m.y, 0.f) * a.y - c.y;
    o1.z = fmaxf(v1.z - m.z, 0.f) * a.z - c.z;
    o1.w = fmaxf(v1.w - m.w, 0.f) * a.w - c.w;
    float4* dst0 = out + (size_t)row0 * (GTILE * F4) + tid;
    float4* dst1 = dst0 + (GTILE * F4);
#pragma unroll
    for (int g = 0; g < GTILE; ++g) {
        dst0[g * F4] = o0;
        dst1[g * F4] = o1;
    }
}

extern "C" void kernel_launch(void* const* d_in, const int* in_sizes, int n_in,
                              void* d_out, int out_size, void* d_ws, size_t ws_size,
                              hipStream_t stream) {
    const float4* xf4 = (const float4*)d_in[0];
    const float* wp   = (const float*)d_in[1];
    float* ws = (float*)d_ws;

    float4* p1   = (float4*)(ws + OFF_P1);
    float4* p2s  = (float4*)(ws + OFF_P2S);
    float4* p2q  = (float4*)(ws + OFF_P2Q);
    float4* mean = (float4*)(ws + OFF_MEAN);
    float*  sc   = ws + OFF_SC;
    float*  cc   = ws + OFF_CC;
    int*    cnt  = (int*)(ws + OFF_CNT);

    k1_colsum   <<<CHUNKS, 512, 0, stream>>>(xf4, p1, cnt);
    k2_relustats<<<CHUNKS, 512, 0, stream>>>(xf4, p1, wp, p2s, p2q, mean, sc, cc, cnt);
    k4_write    <<<BATCH / 2, 256, 0, stream>>>(xf4, mean,
                                                (const float4*)(ws + OFF_SC),
                                                (const float4*)(ws + OFF_CC),
                                                (float4*)d_out);
}

// Round 7
// 157.098 us; speedup vs baseline: 1.1191x; 1.1191x over previous
//
#include <hip/hip_runtime.h>

// Problem constants
#define BATCH 2048
#define FDIM  1024
#define GTILE 16
#define F4    256                 // float4 col-groups per row
#define CHUNKS 128
#define RPC   16                  // rows per chunk

// ws layout (floats) — every buffer fully written before read (poison-safe):
//   p1  [128][1024] @ 0        column partial sums of xf        (512 KB)
//   p2s [128][1024] @ 131072   column partial sums of relu      (512 KB)
//   p2q [128][1024] @ 262144   column partial sumsq             (512 KB)
//   mean[1024]      @ 393216
//   sc  [1024]      @ 394240   wp / sd
//   cc  [1024]      @ 395264   mu * sc
#define OFF_P1   0
#define OFF_P2S  131072
#define OFF_P2Q  262144
#define OFF_MEAN 393216
#define OFF_SC   394240
#define OFF_CC   395264

typedef float v4f __attribute__((ext_vector_type(4)));

__device__ __forceinline__ void v4add(float4& a, const float4& b) {
    a.x += b.x; a.y += b.y; a.z += b.z; a.w += b.w;
}

// ---- k1: column partial sums. 128 blocks x 512 thr.
// thread (cg, h): sums rows chunk*16 + h + 2r, r=0..7; LDS-combine halves.
__global__ void __launch_bounds__(512) k1_colsum(const float4* __restrict__ xf,
                                                 float4* __restrict__ p1) {
    __shared__ float4 lds[512];     // 8 KB
    const int t  = threadIdx.x;
    const int cg = t & 255;
    const int h  = t >> 8;
    const int b  = blockIdx.x;      // chunk
    const float4* p = xf + (size_t)(b * RPC + h) * F4 + cg;
    float4 s = {0.f, 0.f, 0.f, 0.f};
#pragma unroll
    for (int r = 0; r < 8; ++r) v4add(s, p[(size_t)(2 * r) * F4]);
    lds[t] = s;
    __syncthreads();
    if (t < 256) {
        v4add(s, lds[t + 256]);
        p1[b * F4 + t] = s;
    }
}

// ---- k2: redundant split mean-reduce (64 iters/half + LDS combine), then relu
// partial sum/sumsq over this chunk's 16 rows. Block 0 also stores mean.
__global__ void __launch_bounds__(512) k2_relustats(const float4* __restrict__ xf,
                                                    const float4* __restrict__ p1,
                                                    float4* __restrict__ p2s,
                                                    float4* __restrict__ p2q,
                                                    float4* __restrict__ mean4) {
    __shared__ float4 ldsa[512];    // 8 KB
    __shared__ float4 ldsb[512];    // 8 KB
    const int t  = threadIdx.x;
    const int cg = t & 255;
    const int h  = t >> 8;
    const int b  = blockIdx.x;      // chunk

    // split redundant reduce of p1 -> mean (each half does 64 chunks)
    float4 m = {0.f, 0.f, 0.f, 0.f};
#pragma unroll 8
    for (int c = 0; c < 64; ++c) v4add(m, p1[(h * 64 + c) * F4 + cg]);
    ldsa[t] = m;
    __syncthreads();
    m = ldsa[cg];
    v4add(m, ldsa[cg + 256]);
    const float inv_n = 1.0f / (float)BATCH;
    m.x *= inv_n; m.y *= inv_n; m.z *= inv_n; m.w *= inv_n;
    if (b == 0 && t < 256) mean4[t] = m;

    // relu stats over rows chunk*16 + h + 2r
    const float4* p = xf + (size_t)(b * RPC + h) * F4 + cg;
    float4 s = {0.f, 0.f, 0.f, 0.f};
    float4 q = {0.f, 0.f, 0.f, 0.f};
#pragma unroll
    for (int r = 0; r < 8; ++r) {
        float4 v = p[(size_t)(2 * r) * F4];
        float rx = fmaxf(v.x - m.x, 0.f);
        float ry = fmaxf(v.y - m.y, 0.f);
        float rz = fmaxf(v.z - m.z, 0.f);
        float rw = fmaxf(v.w - m.w, 0.f);
        s.x += rx; s.y += ry; s.z += rz; s.w += rw;
        q.x += rx * rx; q.y += ry * ry; q.z += rz * rz; q.w += rw * rw;
    }
    __syncthreads();                 // ldsa being reused
    ldsa[t] = s; ldsb[t] = q;
    __syncthreads();
    if (t < 256) {
        v4add(s, ldsa[t + 256]);
        v4add(q, ldsb[t + 256]);
        p2s[b * F4 + t] = s;
        p2q[b * F4 + t] = q;
    }
}

// ---- k3: reduce p2s/p2q -> sc, cc. 16 blocks x 256 thr, LDS tree (proven). ----
__global__ void __launch_bounds__(256) k3_scale(const float* __restrict__ wp,
                                                const float4* __restrict__ p2s,
                                                const float4* __restrict__ p2q,
                                                float4* __restrict__ sc,
                                                float4* __restrict__ cc) {
    __shared__ float4 rs[256], rq[256];    // 8 KB
    const int t = threadIdx.x;
    const int b = blockIdx.x;              // 0..15
    const int cg = b * 16 + (t & 15);      // col-group
    const int slice = t >> 4;              // 0..15
    const int c0 = slice * (CHUNKS / 16);  // 8 chunks per slice
    float4 s = {0.f,0.f,0.f,0.f}, q = {0.f,0.f,0.f,0.f};
#pragma unroll
    for (int c = c0; c < c0 + CHUNKS / 16; ++c) {
        v4add(s, p2s[c * F4 + cg]);
        v4add(q, p2q[c * F4 + cg]);
    }
    rs[t] = s; rq[t] = q;
    __syncthreads();
    for (int off = 128; off >= 16; off >>= 1) {
        if (t < off) { v4add(rs[t], rs[t + off]); v4add(rq[t], rq[t + off]); }
        __syncthreads();
    }
    if (t < 16) {
        const float inv_n  = 1.0f / (float)BATCH;
        const float inv_n1 = 1.0f / (float)(BATCH - 1);
        const float w = wp[0];
        float4 S = rs[t], Q = rq[t];
        float4 scale, cmb;
        float mu;
        mu = S.x * inv_n; scale.x = w * rsqrtf((Q.x - S.x * mu) * inv_n1); cmb.x = mu * scale.x;
        mu = S.y * inv_n; scale.y = w * rsqrtf((Q.y - S.y * mu) * inv_n1); cmb.y = mu * scale.y;
        mu = S.z * inv_n; scale.z = w * rsqrtf((Q.z - S.z * mu) * inv_n1); cmb.z = mu * scale.z;
        mu = S.w * inv_n; scale.w = w * rsqrtf((Q.w - S.w * mu) * inv_n1); cmb.w = mu * scale.w;
        sc[b * 16 + t] = scale;
        cc[b * 16 + t] = cmb;
    }
}

// ---- k4: fused normalize + 16-way tiled write, non-temporal stores ----
// (output is dead-on-arrival: skip L2 allocation / dirty eviction)
__global__ void __launch_bounds__(256) k4_write(const float4* __restrict__ xf,
                                                const float4* __restrict__ mean,
                                                const float4* __restrict__ sc,
                                                const float4* __restrict__ cc,
                                                float4* __restrict__ out) {
    const int tid  = threadIdx.x;          // 0..255
    const int row0 = blockIdx.x * 2;       // 2 rows per block
    float4 v0 = xf[(size_t)row0 * F4 + tid];
    float4 v1 = xf[(size_t)(row0 + 1) * F4 + tid];
    float4 m = mean[tid];
    float4 a = sc[tid];
    float4 c = cc[tid];
    v4f o0, o1;
    o0.x = fmaxf(v0.x - m.x, 0.f) * a.x - c.x;
    o0.y = fmaxf(v0.y - m.y, 0.f) * a.y - c.y;
    o0.z = fmaxf(v0.z - m.z, 0.f) * a.z - c.z;
    o0.w = fmaxf(v0.w - m.w, 0.f) * a.w - c.w;
    o1.x = fmaxf(v1.x - m.x, 0.f) * a.x - c.x;
    o1.y = fmaxf(v1.y - m.y, 0.f) * a.y - c.y;
    o1.z = fmaxf(v1.z - m.z, 0.f) * a.z - c.z;
    o1.w = fmaxf(v1.w - m.w, 0.f) * a.w - c.w;
    v4f* dst0 = (v4f*)(out + (size_t)row0 * (GTILE * F4) + tid);
    v4f* dst1 = dst0 + (GTILE * F4);
#pragma unroll
    for (int g = 0; g < GTILE; ++g) {
        __builtin_nontemporal_store(o0, dst0 + g * F4);
        __builtin_nontemporal_store(o1, dst1 + g * F4);
    }
}

extern "C" void kernel_launch(void* const* d_in, const int* in_sizes, int n_in,
                              void* d_out, int out_size, void* d_ws, size_t ws_size,
                              hipStream_t stream) {
    const float4* xf4 = (const float4*)d_in[0];
    const float* wp   = (const float*)d_in[1];
    float* ws = (float*)d_ws;

    float4* p1   = (float4*)(ws + OFF_P1);
    float4* p2s  = (float4*)(ws + OFF_P2S);
    float4* p2q  = (float4*)(ws + OFF_P2Q);
    float4* mean = (float4*)(ws + OFF_MEAN);
    float4* sc   = (float4*)(ws + OFF_SC);
    float4* cc   = (float4*)(ws + OFF_CC);

    k1_colsum   <<<CHUNKS, 512, 0, stream>>>(xf4, p1);
    k2_relustats<<<CHUNKS, 512, 0, stream>>>(xf4, p1, p2s, p2q, mean);
    k3_scale    <<<16,     256, 0, stream>>>(wp, p2s, p2q, sc, cc);
    k4_write    <<<BATCH / 2, 256, 0, stream>>>(xf4, mean, sc, cc, (float4*)d_out);
}